// Round 7
// baseline (333.535 us; speedup 1.0000x reference)
//
#include <hip/hip_runtime.h>
#include <math.h>

#define HW 9216
#define Hh 96
#define Ww 96
#define PHW 9604   // 98*98 padded

typedef __attribute__((ext_vector_type(8))) short bh8;
typedef __attribute__((ext_vector_type(4))) short bh4;
typedef __attribute__((ext_vector_type(4))) float f32x4;
typedef __attribute__((ext_vector_type(2))) float f32x2;

__device__ __forceinline__ short f2bf(float f) {
    union { float f; unsigned u; } v; v.f = f;
    unsigned r = v.u + 0x7FFFu + ((v.u >> 16) & 1u);
    return (short)(r >> 16);
}
__device__ __forceinline__ float bf2f(short s) {
    union { unsigned u; float f; } v; v.u = ((unsigned)(unsigned short)s) << 16;
    return v.f;
}

// ---------------------------------------------------------------------------
__global__ void zero_borders(short* __restrict__ xpad1,
                             short* __restrict__ hpa,
                             short* __restrict__ hpb) {
    int i = blockIdx.x * 256 + threadIdx.x;
    const int n1 = 4 * 388 * 224, n2 = 4 * 388 * 64;
    short* p; int C;
    if (i < n1) { p = xpad1; C = 224; }
    else if (i < n1 + n2) { p = hpa; C = 64; i -= n1; }
    else if (i < n1 + 2 * n2) { p = hpb; C = 64; i -= n1 + n2; }
    else return;
    int c = i % C;
    int r = i / C;
    int b = r / 388, pid = r - b * 388;
    int row, col;
    if (pid < 98)       { row = 0;  col = pid; }
    else if (pid < 196) { row = 97; col = pid - 98; }
    else if (pid < 292) { row = pid - 196 + 1; col = 0; }
    else                { row = pid - 292 + 1; col = 97; }
    p[((size_t)b * PHW + row * 98 + col) * C + c] = 0;
}

// concat(extra,flow1,flow2) NCHW fp32 -> padded NHWC bf16 [b][98][98][224]
__global__ void pack_x1(const float* __restrict__ extra,
                        const float* __restrict__ f1,
                        const float* __restrict__ f2,
                        short* __restrict__ xp) {
    __shared__ float t[32][33];
    const int tid = threadIdx.x, tx = tid & 31, ty = tid >> 5;
    const int pt = blockIdx.x, ct = blockIdx.y, b = blockIdx.z;
#pragma unroll
    for (int j = 0; j < 4; ++j) {
        int ch = ct * 32 + ty + j * 8;
        int p = pt * 32 + tx;
        float v = 0.f;
        if (ch < 192)      v = extra[(b * 192 + ch) * HW + p];
        else if (ch < 194) v = f1[(b * 2 + ch - 192) * HW + p];
        else if (ch < 196) v = f2[(b * 2 + ch - 194) * HW + p];
        t[ty + j * 8][tx] = v;
    }
    __syncthreads();
#pragma unroll
    for (int j = 0; j < 4; ++j) {
        int pr = ty + j * 8;
        int p = pt * 32 + pr;
        int r = p / 96, c = p - r * 96;
        xp[((size_t)b * PHW + (r + 1) * 98 + (c + 1)) * 224 + ct * 32 + tx] =
            f2bf(t[tx][pr]);
    }
}

// x NCHW fp32 -> [b][16g][9216pix][8ch] bf16
__global__ void pack_xd(const float* __restrict__ x, short* __restrict__ xd) {
    __shared__ float t[32][33];
    const int tid = threadIdx.x, tx = tid & 31, ty = tid >> 5;
    const int pt = blockIdx.x, ct = blockIdx.y, b = blockIdx.z;
#pragma unroll
    for (int j = 0; j < 4; ++j) {
        int ch = ct * 32 + ty + j * 8;
        t[ty + j * 8][tx] = x[((size_t)b * 128 + ch) * HW + pt * 32 + tx];
    }
    __syncthreads();
    if (tid < 128) {
        int oct = tid >> 5, p = tid & 31;
        int g = (ct * 32 + oct * 8) >> 3;
        bh8 v;
#pragma unroll
        for (int c = 0; c < 8; ++c) v[c] = f2bf(t[oct * 8 + c][p]);
        *(bh8*)&xd[(((size_t)b * 16 + g) * HW + pt * 32 + p) * 8] = v;
    }
}

// ---------------------------------------------------------------------------
__global__ void prep_weights(const float* __restrict__ ow0, const float* __restrict__ ow1,
                             const float* __restrict__ ow2, const float* __restrict__ ow3,
                             const float* __restrict__ wd,
                             short* __restrict__ wb0, short* __restrict__ wb1,
                             short* __restrict__ wb2, short* __restrict__ wb3,
                             short* __restrict__ wbd) {
    int i = blockIdx.x * 256 + threadIdx.x;
    const int n0 = 64 * 9 * 224, n1 = 64 * 9 * 64, n3 = 448 * 9 * 64, nd = 64 * 1152;
    if (i < n0) {
        int co = i / (9 * 224); int r = i - co * (9 * 224);
        int tap = r / 224, ci = r - tap * 224;
        wb0[i] = f2bf(ci < 196 ? ow0[(co * 196 + ci) * 9 + tap] : 0.f);
        return;
    }
    i -= n0;
    if (i < n1) {
        int co = i / (9 * 64); int r = i - co * (9 * 64);
        int tap = r / 64, ci = r - tap * 64;
        wb1[i] = f2bf(ow1[(co * 64 + ci) * 9 + tap]);
        return;
    }
    i -= n1;
    if (i < n1) {
        int co = i / (9 * 64); int r = i - co * (9 * 64);
        int tap = r / 64, ci = r - tap * 64;
        wb2[i] = f2bf(ow2[(co * 64 + ci) * 9 + tap]);
        return;
    }
    i -= n1;
    if (i < n3) {
        int co = i / (9 * 64); int r = i - co * (9 * 64);
        int tap = r / 64, ci = r - tap * 64;
        wb3[i] = f2bf(co < 432 ? ow3[(co * 64 + ci) * 9 + tap] : 0.f);
        return;
    }
    i -= n3;
    if (i < nd) {
        int co = i / 1152, kd = i - co * 1152;
        int gt = kd >> 3, c = kd & 7;
        int g = gt / 9, tap = gt - g * 9;
        wbd[i] = f2bf(wd[(co * 128 + g * 8 + c) * 9 + tap]);
    }
}

// ---------------------------------------------------------------------------
// conv1-3: chunked-weight implicit GEMM. Block = 4 waves over 32 pixels:
// wave = (strip = wv>>1) x (co-half = wv&1, 32 couts). 1152 blocks.
// ---------------------------------------------------------------------------
template<int CINP, int KCH>
__launch_bounds__(256)
__global__ void conv_mfma(const short* __restrict__ xp,
                          const short* __restrict__ wb,
                          const float* __restrict__ bias,
                          short* __restrict__ o1) {
    __shared__ __attribute__((aligned(16))) short smA[9 * 64 * 32];
    const int tid = threadIdx.x;
    const int lane = tid & 63, wv = tid >> 6;
    const int q = lane >> 4, l15 = lane & 15;
    const int b = blockIdx.y;
    const int strip = wv >> 1, coh = wv & 1;
    const int pix0 = blockIdx.x * 32 + strip * 16;
    const int soh = pix0 / 96, sow = pix0 - (pix0 / 96) * 96;

    const short* bp = xp + ((size_t)b * PHW + soh * 98 + sow + l15) * CINP + q * 8;

    const int sco = tid >> 2, sqq = tid & 3;
    const short* wsrc = wb + (size_t)sco * (9 * CINP) + sqq * 8;

    f32x4 acc[2];
#pragma unroll
    for (int t = 0; t < 2; ++t) acc[t] = (f32x4){0.f, 0.f, 0.f, 0.f};

    for (int p = 0; p < KCH; ++p) {
        __syncthreads();
        bh8 wtmp[9];
#pragma unroll
        for (int tap = 0; tap < 9; ++tap)
            wtmp[tap] = *(const bh8*)(wsrc + tap * CINP + p * 32);
#pragma unroll
        for (int tap = 0; tap < 9; ++tap)
            *(bh8*)&smA[tap * 2048 + sco * 32 + sqq * 8] = wtmp[tap];
        __syncthreads();
#pragma unroll
        for (int tap = 0; tap < 9; ++tap) {
            const int ky = tap / 3, kx = tap - (tap / 3) * 3;
            bh8 bf = *(const bh8*)(bp + (ky * 98 + kx) * CINP + p * 32);
#pragma unroll
            for (int t = 0; t < 2; ++t) {
                bh8 af = *(const bh8*)&smA[tap * 2048 + ((coh * 2 + t) * 16 + l15) * 32 + q * 8];
                acc[t] = __builtin_amdgcn_mfma_f32_16x16x32_bf16(af, bf, acc[t], 0, 0, 0);
            }
        }
    }

    size_t base = ((size_t)b * PHW + (soh + 1) * 98 + sow + l15 + 1) * 64;
#pragma unroll
    for (int t = 0; t < 2; ++t) {
        bh4 v4;
#pragma unroll
        for (int r = 0; r < 4; ++r) {
            int co = coh * 32 + t * 16 + q * 4 + r;
            float v = acc[t][r] + bias[co];
            v = (v >= 0.f) ? v : 0.1f * v;
            v4[r] = f2bf(v);
        }
        *(bh4*)(o1 + base + coh * 32 + t * 16 + q * 4) = v4;
    }
}

// ---------------------------------------------------------------------------
// conv4 tiled GEMM: block = 64 co x 192 pix, per-tap K=64 staging (9 phases,
// 18 barriers). LDS rows = 128 B (8 x 16B slots), XOR-swizzled slot' = s^(row&7)
// -> conflict-free staging writes AND fragment reads. Paired f32x2 offset
// stores in the epilogue.
// ---------------------------------------------------------------------------
__launch_bounds__(256)
__global__ void conv4_gemm(const short* __restrict__ xp,
                           const short* __restrict__ wb,
                           const float* __restrict__ bias,
                           float* __restrict__ offp,
                           short* __restrict__ maskb,
                           const float* __restrict__ flow1,
                           const float* __restrict__ flow2) {
    __shared__ __attribute__((aligned(16))) short smA[64 * 64];
    __shared__ __attribute__((aligned(16))) short smB[192 * 64];
    const int tid = threadIdx.x;
    const int lane = tid & 63, wv = tid >> 6;
    const int q = lane >> 4, l15 = lane & 15;
    const int pg = blockIdx.x;           // 48 row-pairs
    const int b = blockIdx.y;
    const int cob = blockIdx.z * 64;
    const int r0 = pg * 2;

    f32x4 acc[3][4];
#pragma unroll
    for (int pf = 0; pf < 3; ++pf)
#pragma unroll
        for (int cf = 0; cf < 4; ++cf) acc[pf][cf] = (f32x4){0.f, 0.f, 0.f, 0.f};

    for (int tap = 0; tap < 9; ++tap) {
        const int ky = tap / 3, kx = tap - (tap / 3) * 3;
        __syncthreads();
        // stage A: 64 rows x 8 slots, 2 slots/thread
#pragma unroll
        for (int it = 0; it < 2; ++it) {
            int id = it * 256 + tid;
            int row = id >> 3, s = id & 7;
            int sw = s ^ (row & 7);
            *(bh8*)&smA[row * 64 + sw * 8] =
                *(const bh8*)(wb + (size_t)(cob + row) * 576 + tap * 64 + s * 8);
        }
        // stage B: 192 rows x 8 slots, 6 slots/thread
#pragma unroll
        for (int it = 0; it < 6; ++it) {
            int id = it * 256 + tid;
            int row = id >> 3, s = id & 7;
            int sw = s ^ (row & 7);
            int srow = (row >= 96) ? 1 : 0;
            int scol = row - srow * 96;
            *(bh8*)&smB[row * 64 + sw * 8] = *(const bh8*)&xp[
                ((size_t)b * PHW + (r0 + srow + ky) * 98 + scol + kx) * 64 + s * 8];
        }
        __syncthreads();
#pragma unroll
        for (int kc = 0; kc < 2; ++kc) {
            bh8 bf[3], af[4];
#pragma unroll
            for (int pf = 0; pf < 3; ++pf) {
                int row = wv * 48 + pf * 16 + l15;
                int sw = (kc * 4 + q) ^ (row & 7);
                bf[pf] = *(const bh8*)&smB[row * 64 + sw * 8];
            }
#pragma unroll
            for (int cf = 0; cf < 4; ++cf) {
                int row = cf * 16 + l15;
                int sw = (kc * 4 + q) ^ (row & 7);
                af[cf] = *(const bh8*)&smA[row * 64 + sw * 8];
            }
#pragma unroll
            for (int pf = 0; pf < 3; ++pf)
#pragma unroll
                for (int cf = 0; cf < 4; ++cf)
                    acc[pf][cf] = __builtin_amdgcn_mfma_f32_16x16x32_bf16(
                        af[cf], bf[pf], acc[pf][cf], 0, 0, 0);
        }
    }

#pragma unroll
    for (int pf = 0; pf < 3; ++pf) {
        int local = wv * 48 + pf * 16 + l15;
        int lrow = (local >= 96) ? 1 : 0;
        int pix = (r0 + lrow) * 96 + (local - lrow * 96);
#pragma unroll
        for (int cf = 0; cf < 4; ++cf) {
            int cb0 = cob + cf * 16 + q * 4;
            if (cb0 < 288) {
                const float* fl = (cb0 < 144) ? flow1 : flow2;
                float fe = fl[(b * 2 + 1) * HW + pix];
                float fo = fl[(b * 2) * HW + pix];
                float t0 = 10.f * tanhf(acc[pf][cf][0] + bias[cb0 + 0]) + fe;
                float t1 = 10.f * tanhf(acc[pf][cf][1] + bias[cb0 + 1]) + fo;
                float t2 = 10.f * tanhf(acc[pf][cf][2] + bias[cb0 + 2]) + fe;
                float t3 = 10.f * tanhf(acc[pf][cf][3] + bias[cb0 + 3]) + fo;
                size_t p0 = ((size_t)b * 144 + (cb0 >> 1)) * HW + pix;
                *(f32x2*)&offp[p0 * 2] = (f32x2){t0, t1};
                *(f32x2*)&offp[(p0 + HW) * 2] = (f32x2){t2, t3};
            } else {
#pragma unroll
                for (int r = 0; r < 4; ++r) {
                    int chn = cb0 + r;
                    if (chn < 432) {
                        float v = acc[pf][cf][r] + bias[chn];
                        maskb[((size_t)b * 144 + (chn - 288)) * HW + pix] =
                            f2bf(1.f / (1.f + expf(-v)));
                    }
                }
            }
        }
    }
}

// ---------------------------------------------------------------------------
// Deform: group-planar xd, packed (dy,dx) pairs, XCD-swizzled blocks.
// ---------------------------------------------------------------------------
__global__ void deform_mfma(const short* __restrict__ xd,
                            const float* __restrict__ offp,
                            const short* __restrict__ maskb,
                            const short* __restrict__ wbd,
                            const float* __restrict__ bias,
                            float* __restrict__ out) {
    __shared__ float red[4][1024];
    const int tid = threadIdx.x;
    const int lane = tid & 63, wv = tid >> 6;
    const int q = lane >> 4, l15 = lane & 15;
    const int blk = blockIdx.x;
    const int xs = blk & 7, idx = blk >> 3;
    const int b = xs >> 1;
    const int pix0 = ((xs & 1) * 288 + idx) * 16;
    const int pix = pix0 + l15;
    const int h = pix / 96, w = pix - (pix / 96) * 96;

    const float* opp = offp + ((size_t)b * 144 * HW + pix) * 2;
    const short* mp = maskb + (size_t)b * 144 * HW + pix;
    const short* xb = xd + (size_t)b * 16 * HW * 8;
    const short* ap = wbd + (size_t)l15 * 1152 + wv * 288 + q * 8;

    f32x2 dxy[9];
    float mk[9];
#pragma unroll
    for (int i = 0; i < 9; ++i) {
        const int gt = wv * 36 + i * 4 + q;
        dxy[i] = *(const f32x2*)(opp + (size_t)gt * HW * 2);
        mk[i] = bf2f(mp[(size_t)gt * HW]);
    }

    f32x4 acc[4];
#pragma unroll
    for (int t = 0; t < 4; ++t) acc[t] = (f32x4){0.f, 0.f, 0.f, 0.f};

#pragma unroll
    for (int i = 0; i < 9; ++i) {
        const int gt = wv * 36 + i * 4 + q;
        const int g = gt / 9, tap = gt - (gt / 9) * 9;
        float py = dxy[i][0] + (float)(tap / 3) + (float)h - 1.f;
        float px = dxy[i][1] + (float)(tap - (tap / 3) * 3) + (float)w - 1.f;
        float y0f = floorf(py), x0f = floorf(px);
        float wy1 = py - y0f, wx1 = px - x0f;
        float wy0 = 1.f - wy1, wx0 = 1.f - wx1;
        int y0 = (int)y0f, x0 = (int)x0f;
        int y1 = y0 + 1, x1 = x0 + 1;
        bool vy0 = (y0 >= 0) && (y0 < Hh), vy1 = (y1 >= 0) && (y1 < Hh);
        bool vx0 = (x0 >= 0) && (x0 < Ww), vx1 = (x1 >= 0) && (x1 < Ww);
        int cy0 = min(max(y0, 0), Hh - 1), cy1 = min(max(y1, 0), Hh - 1);
        int cx0 = min(max(x0, 0), Ww - 1), cx1 = min(max(x1, 0), Ww - 1);
        float m = mk[i];
        float w00 = wy0 * wx0 * ((vy0 && vx0) ? m : 0.f);
        float w01 = wy0 * wx1 * ((vy0 && vx1) ? m : 0.f);
        float w10 = wy1 * wx0 * ((vy1 && vx0) ? m : 0.f);
        float w11 = wy1 * wx1 * ((vy1 && vx1) ? m : 0.f);
        const short* cb = xb + (size_t)g * HW * 8;
        bh8 a00 = *(const bh8*)(cb + (size_t)(cy0 * 96 + cx0) * 8);
        bh8 a01 = *(const bh8*)(cb + (size_t)(cy0 * 96 + cx1) * 8);
        bh8 a10 = *(const bh8*)(cb + (size_t)(cy1 * 96 + cx0) * 8);
        bh8 a11 = *(const bh8*)(cb + (size_t)(cy1 * 96 + cx1) * 8);
        bh8 bf;
#pragma unroll
        for (int c = 0; c < 8; ++c) {
            float s = w00 * bf2f(a00[c]) + w01 * bf2f(a01[c])
                    + w10 * bf2f(a10[c]) + w11 * bf2f(a11[c]);
            bf[c] = f2bf(s);
        }
#pragma unroll
        for (int t = 0; t < 4; ++t) {
            bh8 af = *(const bh8*)(ap + (size_t)t * 16 * 1152 + i * 32);
            acc[t] = __builtin_amdgcn_mfma_f32_16x16x32_bf16(af, bf, acc[t], 0, 0, 0);
        }
    }

#pragma unroll
    for (int t = 0; t < 4; ++t)
#pragma unroll
        for (int r = 0; r < 4; ++r)
            red[wv][(t * 16 + q * 4 + r) * 16 + l15] = acc[t][r];
    __syncthreads();
    for (int e = tid; e < 1024; e += 256) {
        int co = e >> 4, pl = e & 15;
        float v = red[0][e] + red[1][e] + red[2][e] + red[3][e] + bias[co];
        out[((size_t)b * 64 + co) * HW + pix0 + pl] = v;
    }
}

// ---------------------------------------------------------------------------
extern "C" void kernel_launch(void* const* d_in, const int* in_sizes, int n_in,
                              void* d_out, int out_size, void* d_ws, size_t ws_size,
                              hipStream_t stream) {
    const float* x      = (const float*)d_in[0];
    const float* extra  = (const float*)d_in[1];
    const float* flow1  = (const float*)d_in[2];
    const float* flow2  = (const float*)d_in[3];
    const float* weight = (const float*)d_in[4];
    const float* bias   = (const float*)d_in[5];
    const float* ow0    = (const float*)d_in[6];
    const float* ob0    = (const float*)d_in[7];
    const float* ow1    = (const float*)d_in[8];
    const float* ob1    = (const float*)d_in[9];
    const float* ow2    = (const float*)d_in[10];
    const float* ob2    = (const float*)d_in[11];
    const float* ow3    = (const float*)d_in[12];
    const float* ob3    = (const float*)d_in[13];
    float* out = (float*)d_out;

    char* wsb = (char*)d_ws;
    short* xpad1 = (short*)wsb;   wsb += (size_t)4 * PHW * 224 * 2;
    short* hpa   = (short*)wsb;   wsb += (size_t)4 * PHW * 64 * 2;
    short* hpb   = (short*)wsb;   wsb += (size_t)4 * PHW * 64 * 2;
    float* offpair = (float*)wsb; wsb += (size_t)4 * 144 * HW * 2 * 4;
    short* maskbuf = (short*)wsb; wsb += (size_t)4 * 144 * HW * 2;
    short* xd      = (short*)wsb; wsb += (size_t)4 * 16 * HW * 8 * 2 + 32;
    short* wb0     = (short*)wsb; wsb += 64 * 9 * 224 * 2;
    short* wb1     = (short*)wsb; wsb += 64 * 9 * 64 * 2;
    short* wb2     = (short*)wsb; wsb += 64 * 9 * 64 * 2;
    short* wb3     = (short*)wsb; wsb += 448 * 9 * 64 * 2;
    short* wbd     = (short*)wsb;

    auto g1 = [](int n) { return dim3((n + 255) / 256); };
    zero_borders<<<g1(4 * 388 * 352), 256, 0, stream>>>(xpad1, hpa, hpb);
    pack_x1<<<dim3(288, 7, 4), 256, 0, stream>>>(extra, flow1, flow2, xpad1);
    pack_xd<<<dim3(288, 4, 4), 256, 0, stream>>>(x, xd);
    prep_weights<<<g1(534528), 256, 0, stream>>>(ow0, ow1, ow2, ow3, weight,
                                                 wb0, wb1, wb2, wb3, wbd);

    conv_mfma<224, 7><<<dim3(288, 4), 256, 0, stream>>>(xpad1, wb0, ob0, hpa);
    conv_mfma<64, 2><<<dim3(288, 4), 256, 0, stream>>>(hpa, wb1, ob1, hpb);
    conv_mfma<64, 2><<<dim3(288, 4), 256, 0, stream>>>(hpb, wb2, ob2, hpa);
    conv4_gemm<<<dim3(48, 4, 7), 256, 0, stream>>>(hpa, wb3, ob3, offpair,
                                                   maskbuf, flow1, flow2);
    deform_mfma<<<dim3(2304), 256, 0, stream>>>(xd, offpair, maskbuf, wbd, bias, out);
}

// Round 8
// 291.368 us; speedup vs baseline: 1.1447x; 1.1447x over previous
//
#include <hip/hip_runtime.h>
#include <math.h>

#define HW 9216
#define Hh 96
#define Ww 96
#define PHW 9604   // 98*98 padded

typedef __attribute__((ext_vector_type(8))) short bh8;
typedef __attribute__((ext_vector_type(4))) short bh4;
typedef __attribute__((ext_vector_type(4))) float f32x4;
typedef __attribute__((ext_vector_type(2))) float f32x2;
typedef __attribute__((ext_vector_type(4))) int i32x4;
union bh8i { bh8 v; i32x4 i; };

__device__ __forceinline__ short f2bf(float f) {
    union { float f; unsigned u; } v; v.f = f;
    unsigned r = v.u + 0x7FFFu + ((v.u >> 16) & 1u);
    return (short)(r >> 16);
}
__device__ __forceinline__ float bf2f(short s) {
    union { unsigned u; float f; } v; v.u = ((unsigned)(unsigned short)s) << 16;
    return v.f;
}
__device__ __forceinline__ float lo_bf(unsigned u) {
    union { unsigned u; float f; } v; v.u = u << 16; return v.f;
}
__device__ __forceinline__ float hi_bf(unsigned u) {
    union { unsigned u; float f; } v; v.u = u & 0xFFFF0000u; return v.f;
}
__device__ __forceinline__ unsigned pack_bf2(float lo, float hi) {
    union { float f; unsigned u; } a, b; a.f = lo; b.f = hi;
    unsigned ul = a.u + 0x7FFFu + ((a.u >> 16) & 1u);
    unsigned uh = b.u + 0x7FFFu + ((b.u >> 16) & 1u);
    return (ul >> 16) | (uh & 0xFFFF0000u);
}

// ---------------------------------------------------------------------------
// Fused misc prep: pad-border zeroing (xpad1/hpa/hpb/xdp) + all weight prep.
__global__ void prep_misc(short* __restrict__ xpad1, short* __restrict__ hpa,
                          short* __restrict__ hpb, short* __restrict__ xdp,
                          const float* __restrict__ ow0, const float* __restrict__ ow1,
                          const float* __restrict__ ow2, const float* __restrict__ ow3,
                          const float* __restrict__ wd,
                          short* __restrict__ wb0, short* __restrict__ wb1,
                          short* __restrict__ wb2, short* __restrict__ wb3,
                          short* __restrict__ wbd) {
    int i = blockIdx.x * 256 + threadIdx.x;
    const int z1 = 4 * 388 * 224, z2 = 4 * 388 * 64;
    // --- segment A: borders of xpad1/hpa/hpb
    if (i < z1 + 2 * z2) {
        short* p; int C;
        if (i < z1) { p = xpad1; C = 224; }
        else if (i < z1 + z2) { p = hpa; C = 64; i -= z1; }
        else { p = hpb; C = 64; i -= z1 + z2; }
        int c = i % C;
        int r = i / C;
        int b = r / 388, pid = r - b * 388;
        int row, col;
        if (pid < 98)       { row = 0;  col = pid; }
        else if (pid < 196) { row = 97; col = pid - 98; }
        else if (pid < 292) { row = pid - 196 + 1; col = 0; }
        else                { row = pid - 292 + 1; col = 97; }
        p[((size_t)b * PHW + row * 98 + col) * C + c] = 0;
        return;
    }
    i -= z1 + 2 * z2;
    // --- segment B: ring of xdp (per b,g)
    const int zr = 4 * 16 * 388 * 8;
    if (i < zr) {
        int c8 = i & 7;
        int r = i >> 3;
        int pid = r % 388;
        int bg = r / 388;
        int row, col;
        if (pid < 98)       { row = 0;  col = pid; }
        else if (pid < 196) { row = 97; col = pid - 98; }
        else if (pid < 292) { row = pid - 196 + 1; col = 0; }
        else                { row = pid - 292 + 1; col = 97; }
        xdp[((size_t)bg * PHW + row * 98 + col) * 8 + c8] = 0;
        return;
    }
    i -= zr;
    // --- segment C: weights
    const int n0 = 64 * 9 * 224, n1 = 64 * 9 * 64, n3 = 448 * 9 * 64, nd = 64 * 1152;
    if (i < n0) {
        int co = i / (9 * 224); int r = i - co * (9 * 224);
        int tap = r / 224, ci = r - tap * 224;
        wb0[i] = f2bf(ci < 196 ? ow0[(co * 196 + ci) * 9 + tap] : 0.f);
        return;
    }
    i -= n0;
    if (i < n1) {
        int co = i / (9 * 64); int r = i - co * (9 * 64);
        int tap = r / 64, ci = r - tap * 64;
        wb1[i] = f2bf(ow1[(co * 64 + ci) * 9 + tap]);
        return;
    }
    i -= n1;
    if (i < n1) {
        int co = i / (9 * 64); int r = i - co * (9 * 64);
        int tap = r / 64, ci = r - tap * 64;
        wb2[i] = f2bf(ow2[(co * 64 + ci) * 9 + tap]);
        return;
    }
    i -= n1;
    if (i < n3) {
        int co = i / (9 * 64); int r = i - co * (9 * 64);
        int tap = r / 64, ci = r - tap * 64;
        wb3[i] = f2bf(co < 432 ? ow3[(co * 64 + ci) * 9 + tap] : 0.f);
        return;
    }
    i -= n3;
    if (i < nd) {
        int co = i / 1152, kd = i - co * 1152;
        int gt = kd >> 3, c = kd & 7;
        int g = gt / 9, tap = gt - g * 9;
        wbd[i] = f2bf(wd[(co * 128 + g * 8 + c) * 9 + tap]);
    }
}

// ---------------------------------------------------------------------------
// Fused packers. y<7: concat->xpad1 (ct=y). y>=7: x->xdp padded group-planar.
__global__ void pack_all(const float* __restrict__ extra,
                         const float* __restrict__ f1,
                         const float* __restrict__ f2,
                         const float* __restrict__ x,
                         short* __restrict__ xp,
                         short* __restrict__ xdp) {
    __shared__ float t[32][33];
    const int tid = threadIdx.x, tx = tid & 31, ty = tid >> 5;
    const int pt = blockIdx.x, b = blockIdx.z;
    if (blockIdx.y < 7) {
        const int ct = blockIdx.y;
#pragma unroll
        for (int j = 0; j < 4; ++j) {
            int ch = ct * 32 + ty + j * 8;
            int p = pt * 32 + tx;
            float v = 0.f;
            if (ch < 192)      v = extra[(b * 192 + ch) * HW + p];
            else if (ch < 194) v = f1[(b * 2 + ch - 192) * HW + p];
            else if (ch < 196) v = f2[(b * 2 + ch - 194) * HW + p];
            t[ty + j * 8][tx] = v;
        }
        __syncthreads();
#pragma unroll
        for (int j = 0; j < 4; ++j) {
            int pr = ty + j * 8;
            int p = pt * 32 + pr;
            int r = p / 96, c = p - r * 96;
            xp[((size_t)b * PHW + (r + 1) * 98 + (c + 1)) * 224 + ct * 32 + tx] =
                f2bf(t[tx][pr]);
        }
    } else {
        const int ct = blockIdx.y - 7;
#pragma unroll
        for (int j = 0; j < 4; ++j) {
            int ch = ct * 32 + ty + j * 8;
            t[ty + j * 8][tx] = x[((size_t)b * 128 + ch) * HW + pt * 32 + tx];
        }
        __syncthreads();
        if (tid < 128) {
            int oct = tid >> 5, p = tid & 31;
            int g = ct * 4 + oct;
            int pix = pt * 32 + p;
            int r = pix / 96, c = pix - r * 96;
            bh8 v;
#pragma unroll
            for (int cc = 0; cc < 8; ++cc) v[cc] = f2bf(t[oct * 8 + cc][p]);
            *(bh8*)&xdp[(((size_t)b * 16 + g) * PHW + (r + 1) * 98 + (c + 1)) * 8] = v;
        }
    }
}

// ---------------------------------------------------------------------------
// conv1-3 (round-6 structure): block = 4 waves x (16px x 64co), weight chunk
// staged in LDS per 32-cin chunk, B-frags direct 16B global loads.
// ---------------------------------------------------------------------------
template<int CINP, int KCH>
__launch_bounds__(256)
__global__ void conv_mfma(const short* __restrict__ xp,
                          const short* __restrict__ wb,
                          const float* __restrict__ bias,
                          short* __restrict__ o1) {
    __shared__ __attribute__((aligned(16))) short smA[9 * 64 * 32];
    const int tid = threadIdx.x;
    const int lane = tid & 63, wv = tid >> 6;
    const int q = lane >> 4, l15 = lane & 15;
    const int b = blockIdx.y;
    const int pix0 = blockIdx.x * 64 + wv * 16;
    const int soh = pix0 / 96, sow = pix0 - (pix0 / 96) * 96;

    const short* bp = xp + ((size_t)b * PHW + soh * 98 + sow + l15) * CINP + q * 8;

    const int sco = tid >> 2, sqq = tid & 3;
    const short* wsrc = wb + (size_t)sco * (9 * CINP) + sqq * 8;

    f32x4 acc[4];
#pragma unroll
    for (int t = 0; t < 4; ++t) acc[t] = (f32x4){0.f, 0.f, 0.f, 0.f};

    for (int p = 0; p < KCH; ++p) {
        __syncthreads();
        bh8 wtmp[9];
#pragma unroll
        for (int tap = 0; tap < 9; ++tap)
            wtmp[tap] = *(const bh8*)(wsrc + tap * CINP + p * 32);
#pragma unroll
        for (int tap = 0; tap < 9; ++tap)
            *(bh8*)&smA[tap * 2048 + sco * 32 + sqq * 8] = wtmp[tap];
        __syncthreads();
#pragma unroll
        for (int tap = 0; tap < 9; ++tap) {
            const int ky = tap / 3, kx = tap - (tap / 3) * 3;
            bh8 bf = *(const bh8*)(bp + (ky * 98 + kx) * CINP + p * 32);
#pragma unroll
            for (int t = 0; t < 4; ++t) {
                bh8 af = *(const bh8*)&smA[tap * 2048 + (t * 16 + l15) * 32 + q * 8];
                acc[t] = __builtin_amdgcn_mfma_f32_16x16x32_bf16(af, bf, acc[t], 0, 0, 0);
            }
        }
    }

    size_t base = ((size_t)b * PHW + (soh + 1) * 98 + sow + l15 + 1) * 64;
#pragma unroll
    for (int t = 0; t < 4; ++t) {
        bh4 v4;
#pragma unroll
        for (int r = 0; r < 4; ++r) {
            int co = t * 16 + q * 4 + r;
            float v = acc[t][r] + bias[co];
            v = (v >= 0.f) ? v : 0.1f * v;
            v4[r] = f2bf(v);
        }
        *(bh4*)(o1 + base + t * 16 + q * 4) = v4;
    }
}

// ---------------------------------------------------------------------------
// conv4 tiled GEMM with XOR-swizzled LDS (conflict-free), per-tap staging.
// ---------------------------------------------------------------------------
__launch_bounds__(256)
__global__ void conv4_gemm(const short* __restrict__ xp,
                           const short* __restrict__ wb,
                           const float* __restrict__ bias,
                           float* __restrict__ offp,
                           short* __restrict__ maskb,
                           const float* __restrict__ flow1,
                           const float* __restrict__ flow2) {
    __shared__ __attribute__((aligned(16))) short smA[64 * 64];
    __shared__ __attribute__((aligned(16))) short smB[192 * 64];
    const int tid = threadIdx.x;
    const int lane = tid & 63, wv = tid >> 6;
    const int q = lane >> 4, l15 = lane & 15;
    const int pg = blockIdx.x;
    const int b = blockIdx.y;
    const int cob = blockIdx.z * 64;
    const int r0 = pg * 2;

    f32x4 acc[3][4];
#pragma unroll
    for (int pf = 0; pf < 3; ++pf)
#pragma unroll
        for (int cf = 0; cf < 4; ++cf) acc[pf][cf] = (f32x4){0.f, 0.f, 0.f, 0.f};

    for (int tap = 0; tap < 9; ++tap) {
        const int ky = tap / 3, kx = tap - (tap / 3) * 3;
        __syncthreads();
#pragma unroll
        for (int it = 0; it < 2; ++it) {
            int id = it * 256 + tid;
            int row = id >> 3, s = id & 7;
            int sw = s ^ (row & 7);
            *(bh8*)&smA[row * 64 + sw * 8] =
                *(const bh8*)(wb + (size_t)(cob + row) * 576 + tap * 64 + s * 8);
        }
#pragma unroll
        for (int it = 0; it < 6; ++it) {
            int id = it * 256 + tid;
            int row = id >> 3, s = id & 7;
            int sw = s ^ (row & 7);
            int srow = (row >= 96) ? 1 : 0;
            int scol = row - srow * 96;
            *(bh8*)&smB[row * 64 + sw * 8] = *(const bh8*)&xp[
                ((size_t)b * PHW + (r0 + srow + ky) * 98 + scol + kx) * 64 + s * 8];
        }
        __syncthreads();
#pragma unroll
        for (int kc = 0; kc < 2; ++kc) {
            bh8 bf[3], af[4];
#pragma unroll
            for (int pf = 0; pf < 3; ++pf) {
                int row = wv * 48 + pf * 16 + l15;
                int sw = (kc * 4 + q) ^ (row & 7);
                bf[pf] = *(const bh8*)&smB[row * 64 + sw * 8];
            }
#pragma unroll
            for (int cf = 0; cf < 4; ++cf) {
                int row = cf * 16 + l15;
                int sw = (kc * 4 + q) ^ (row & 7);
                af[cf] = *(const bh8*)&smA[row * 64 + sw * 8];
            }
#pragma unroll
            for (int pf = 0; pf < 3; ++pf)
#pragma unroll
                for (int cf = 0; cf < 4; ++cf)
                    acc[pf][cf] = __builtin_amdgcn_mfma_f32_16x16x32_bf16(
                        af[cf], bf[pf], acc[pf][cf], 0, 0, 0);
        }
    }

#pragma unroll
    for (int pf = 0; pf < 3; ++pf) {
        int local = wv * 48 + pf * 16 + l15;
        int lrow = (local >= 96) ? 1 : 0;
        int pix = (r0 + lrow) * 96 + (local - lrow * 96);
#pragma unroll
        for (int cf = 0; cf < 4; ++cf) {
            int cb0 = cob + cf * 16 + q * 4;
            if (cb0 < 288) {
                const float* fl = (cb0 < 144) ? flow1 : flow2;
                float fe = fl[(b * 2 + 1) * HW + pix];
                float fo = fl[(b * 2) * HW + pix];
                float t0 = 10.f * tanhf(acc[pf][cf][0] + bias[cb0 + 0]) + fe;
                float t1 = 10.f * tanhf(acc[pf][cf][1] + bias[cb0 + 1]) + fo;
                float t2 = 10.f * tanhf(acc[pf][cf][2] + bias[cb0 + 2]) + fe;
                float t3 = 10.f * tanhf(acc[pf][cf][3] + bias[cb0 + 3]) + fo;
                size_t p0 = ((size_t)b * 144 + (cb0 >> 1)) * HW + pix;
                *(f32x2*)&offp[p0 * 2] = (f32x2){t0, t1};
                *(f32x2*)&offp[(p0 + HW) * 2] = (f32x2){t2, t3};
            } else {
#pragma unroll
                for (int r = 0; r < 4; ++r) {
                    int chn = cb0 + r;
                    if (chn < 432) {
                        float v = acc[pf][cf][r] + bias[chn];
                        maskb[((size_t)b * 144 + (chn - 288)) * HW + pix] =
                            f2bf(1.f / (1.f + expf(-v)));
                    }
                }
            }
        }
    }
}

// ---------------------------------------------------------------------------
// Deform: padded zero-ring xdp (no masks/bounds: clamp coords to [-1,96]),
// fast packed bf16 unpack/pack, all 9 pointers+weights precomputed so loads
// can be hoisted deep. XCD-swizzled blocks.
// ---------------------------------------------------------------------------
__launch_bounds__(256)
__global__ void deform_mfma(const short* __restrict__ xdp,
                            const float* __restrict__ offp,
                            const short* __restrict__ maskb,
                            const short* __restrict__ wbd,
                            const float* __restrict__ bias,
                            float* __restrict__ out) {
    __shared__ float red[4][1024];
    const int tid = threadIdx.x;
    const int lane = tid & 63, wv = tid >> 6;
    const int q = lane >> 4, l15 = lane & 15;
    const int blk = blockIdx.x;
    const int xs = blk & 7, idx = blk >> 3;
    const int b = xs >> 1;
    const int pix0 = ((xs & 1) * 288 + idx) * 16;
    const int pix = pix0 + l15;
    const int h = pix / 96, w = pix - (pix / 96) * 96;

    const float* opp = offp + ((size_t)b * 144 * HW + pix) * 2;
    const short* mp = maskb + (size_t)b * 144 * HW + pix;
    const short* xb = xdp + (size_t)b * 16 * PHW * 8;
    const short* ap = wbd + (size_t)l15 * 1152 + wv * 288 + q * 8;

    f32x2 dxy[9];
    float mk[9];
#pragma unroll
    for (int i = 0; i < 9; ++i) {
        const int gt = wv * 36 + i * 4 + q;
        dxy[i] = *(const f32x2*)(opp + (size_t)gt * HW * 2);
        mk[i] = bf2f(mp[(size_t)gt * HW]);
    }

    // precompute pointers + weights for all 9 samples
    const short* cp[9];
    f32x4 ww[9];
#pragma unroll
    for (int i = 0; i < 9; ++i) {
        const int gt = wv * 36 + i * 4 + q;
        const int g = gt / 9, tap = gt - (gt / 9) * 9;
        float py = dxy[i][0] + (float)(tap / 3) + (float)h - 1.f;
        float px = dxy[i][1] + (float)(tap - (tap / 3) * 3) + (float)w - 1.f;
        py = fminf(fmaxf(py, -1.f), 96.f);
        px = fminf(fmaxf(px, -1.f), 96.f);
        float y0f = floorf(py), x0f = floorf(px);
        float wy1 = py - y0f, wx1 = px - x0f;
        float wy0 = 1.f - wy1, wx0 = 1.f - wx1;
        int yp = (int)y0f + 1, xp = (int)x0f + 1;
        cp[i] = xb + ((size_t)g * PHW + yp * 98 + xp) * 8;
        float m = mk[i];
        ww[i] = (f32x4){wy0 * wx0 * m, wy0 * wx1 * m, wy1 * wx0 * m, wy1 * wx1 * m};
    }

    f32x4 acc[4];
#pragma unroll
    for (int t = 0; t < 4; ++t) acc[t] = (f32x4){0.f, 0.f, 0.f, 0.f};

#pragma unroll
    for (int i = 0; i < 9; ++i) {
        bh8i c00, c01, c10, c11;
        c00.v = *(const bh8*)(cp[i]);
        c01.v = *(const bh8*)(cp[i] + 8);
        c10.v = *(const bh8*)(cp[i] + 98 * 8);
        c11.v = *(const bh8*)(cp[i] + 99 * 8);
        const float w00 = ww[i][0], w01 = ww[i][1], w10 = ww[i][2], w11 = ww[i][3];
        bh8i bf;
#pragma unroll
        for (int k = 0; k < 4; ++k) {
            unsigned u00 = (unsigned)c00.i[k], u01 = (unsigned)c01.i[k];
            unsigned u10 = (unsigned)c10.i[k], u11 = (unsigned)c11.i[k];
            float lo = w00 * lo_bf(u00) + w01 * lo_bf(u01)
                     + w10 * lo_bf(u10) + w11 * lo_bf(u11);
            float hi = w00 * hi_bf(u00) + w01 * hi_bf(u01)
                     + w10 * hi_bf(u10) + w11 * hi_bf(u11);
            bf.i[k] = (int)pack_bf2(lo, hi);
        }
#pragma unroll
        for (int t = 0; t < 4; ++t) {
            bh8 af = *(const bh8*)(ap + (size_t)t * 16 * 1152 + i * 32);
            acc[t] = __builtin_amdgcn_mfma_f32_16x16x32_bf16(af, bf.v, acc[t], 0, 0, 0);
        }
    }

#pragma unroll
    for (int t = 0; t < 4; ++t)
#pragma unroll
        for (int r = 0; r < 4; ++r)
            red[wv][(t * 16 + q * 4 + r) * 16 + l15] = acc[t][r];
    __syncthreads();
    for (int e = tid; e < 1024; e += 256) {
        int co = e >> 4, pl = e & 15;
        float v = red[0][e] + red[1][e] + red[2][e] + red[3][e] + bias[co];
        out[((size_t)b * 64 + co) * HW + pix0 + pl] = v;
    }
}

// ---------------------------------------------------------------------------
extern "C" void kernel_launch(void* const* d_in, const int* in_sizes, int n_in,
                              void* d_out, int out_size, void* d_ws, size_t ws_size,
                              hipStream_t stream) {
    const float* x      = (const float*)d_in[0];
    const float* extra  = (const float*)d_in[1];
    const float* flow1  = (const float*)d_in[2];
    const float* flow2  = (const float*)d_in[3];
    const float* weight = (const float*)d_in[4];
    const float* bias   = (const float*)d_in[5];
    const float* ow0    = (const float*)d_in[6];
    const float* ob0    = (const float*)d_in[7];
    const float* ow1    = (const float*)d_in[8];
    const float* ob1    = (const float*)d_in[9];
    const float* ow2    = (const float*)d_in[10];
    const float* ob2    = (const float*)d_in[11];
    const float* ow3    = (const float*)d_in[12];
    const float* ob3    = (const float*)d_in[13];
    float* out = (float*)d_out;

    char* wsb = (char*)d_ws;
    short* xpad1 = (short*)wsb;   wsb += (size_t)4 * PHW * 224 * 2;
    short* hpa   = (short*)wsb;   wsb += (size_t)4 * PHW * 64 * 2;
    short* hpb   = (short*)wsb;   wsb += (size_t)4 * PHW * 64 * 2;
    float* offpair = (float*)wsb; wsb += (size_t)4 * 144 * HW * 2 * 4;
    short* maskbuf = (short*)wsb; wsb += (size_t)4 * 144 * HW * 2;
    short* xdp     = (short*)wsb; wsb += (size_t)4 * 16 * PHW * 8 * 2 + 32;
    short* wb0     = (short*)wsb; wsb += 64 * 9 * 224 * 2;
    short* wb1     = (short*)wsb; wsb += 64 * 9 * 64 * 2;
    short* wb2     = (short*)wsb; wsb += 64 * 9 * 64 * 2;
    short* wb3     = (short*)wsb; wsb += 448 * 9 * 64 * 2;
    short* wbd     = (short*)wsb;

    // prep_misc total elements: borders 546304 + xdp ring 198656 + weights 534528
    const int prep_total = 546304 + 198656 + 534528;
    prep_misc<<<dim3((prep_total + 255) / 256), 256, 0, stream>>>(
        xpad1, hpa, hpb, xdp, ow0, ow1, ow2, ow3, weight,
        wb0, wb1, wb2, wb3, wbd);
    pack_all<<<dim3(288, 11, 4), 256, 0, stream>>>(extra, flow1, flow2, x, xpad1, xdp);

    conv_mfma<224, 7><<<dim3(144, 4), 256, 0, stream>>>(xpad1, wb0, ob0, hpa);
    conv_mfma<64, 2><<<dim3(144, 4), 256, 0, stream>>>(hpa, wb1, ob1, hpb);
    conv_mfma<64, 2><<<dim3(144, 4), 256, 0, stream>>>(hpb, wb2, ob2, hpa);
    conv4_gemm<<<dim3(48, 4, 7), 256, 0, stream>>>(hpa, wb3, ob3, offpair,
                                                   maskbuf, flow1, flow2);
    deform_mfma<<<dim3(2304), 256, 0, stream>>>(xdp, offpair, maskbuf, wbd, bias, out);
}